// Round 9
// baseline (263.318 us; speedup 1.0000x reference)
//
#include <hip/hip_runtime.h>
#include <hip/hip_fp16.h>
#include <math.h>

#define N_NODES 50000
#define N_EDGES 800000
#define F_IN    128
#define D_HID   96
#define NHEAD   8
#define DH      12
#define N_CLS   40
#define NEG_SLOPE 0.2f

#define NPART   (N_NODES / 8)        // 6250 dst nodes per XCD group
#define NWCHUNK 256                  // edge chunks per group
#define ECHUNK  (N_EDGES / NWCHUNK)  // 3125 edges per chunk
#define NHISTB  (8 * NWCHUNK)        // 2048 hist/fill blocks

#define GBM 64                       // gemm rows per block
#define NGB ((N_NODES + GBM - 1) / GBM)   // 782
#define WPAD 136                     // LDS W row pad (272B: 16B aligned, 2-way banks = free)

typedef _Float16 f16x8 __attribute__((ext_vector_type(8)));
typedef float    f32x4 __attribute__((ext_vector_type(4)));

// ---------------- pre: zero cnt + fp16-transpose W0/W1 + fp32-transpose Wout ----------
// blocks [0,49): zero cnt; [49,97): wt0[n*128+k]=W0[k*96+n]; [97,133): wt1[n*96+k]=W1[k*96+n];
// [133,148): woutT[c*96+r]=Wout[r*40+c]
__global__ __launch_bounds__(256) void pre_kernel(
    int4* __restrict__ cnt4, const float* __restrict__ W0, const float* __restrict__ W1,
    const float* __restrict__ Wout,
    _Float16* __restrict__ wt0, _Float16* __restrict__ wt1, float* __restrict__ woutT)
{
    int b = blockIdx.x, t = threadIdx.x;
    if (b < 49) {
        int i = b * 256 + t;
        if (i < 12504) cnt4[i] = make_int4(0, 0, 0, 0);
    } else if (b < 97) {
        int idx = (b - 49) * 256 + t;          // idx = n*128+k (write-coalesced)
        int n = idx >> 7, k = idx & 127;
        wt0[idx] = (_Float16)W0[k * D_HID + n];
    } else if (b < 133) {
        int idx = (b - 97) * 256 + t;          // idx = n*96+k
        int n = idx / 96, k = idx - n * 96;
        wt1[idx] = (_Float16)W1[k * D_HID + n];
    } else {
        int idx = (b - 133) * 256 + t;         // idx = c*96+r
        if (idx < N_CLS * D_HID) {
            int c = idx / 96, r = idx - c * 96;
            woutT[idx] = Wout[r * N_CLS + c];
        }
    }
}

// ---------------- MFMA GEMM core: H = A[M,K] @ W[K,96] (fp16 in, fp32 acc) ------------
// Wave w: rows [bid*64+16w, +16) x 96 cols via 6 x mfma_f32_16x16x32_f16.
// Fragments (verified r7/m89): A row=lane&15, k=8*(lane>>4)+j; B col=lane&15 same k;
// D col=lane&15, row=4*(lane>>4)+r. W staged once (16B copies, one barrier); A-fragments
// loaded straight from global (row-local => OOB rows can't pollute valid rows).
__device__ __forceinline__ void gemm_alpha_mfma_body(
    const float* __restrict__ A, const _Float16* __restrict__ WT,
    const float* __restrict__ asrc, const float* __restrict__ adst,
    __half* __restrict__ Hout, float* __restrict__ aS, float* __restrict__ aD,
    int M, int K, int bid,
    _Float16 (*Wt)[WPAD], _Float16 (*Hl)[104], float* avl, float* adl)
{
    int tid  = threadIdx.x;
    int lane = tid & 63;
    int w    = tid >> 6;
    int n0   = bid * GBM;

    // stage WT [96][K] -> Wt[96][WPAD] as 16B chunks (conflict-free)
    int cpr = K >> 3;                 // 16B chunks per row
    int nch = 96 * cpr;
    for (int ch = tid; ch < nch; ch += 256) {
        int row = ch / cpr, off = (ch - row * cpr) << 3;
        *(f16x8*)&Wt[row][off] = *(const f16x8*)&WT[row * K + off];
    }
    if (tid < 96) { avl[tid] = asrc[tid]; adl[tid] = adst[tid]; }
    __syncthreads();

    int c  = lane & 15;
    int kg = lane >> 4;
    int arow = n0 + (w << 4) + c;
    const float* ap = A + (size_t)(arow < M ? arow : M - 1) * K + (kg << 3);

    f32x4 acc[6];
#pragma unroll
    for (int t = 0; t < 6; t++) acc[t] = (f32x4){0.f, 0.f, 0.f, 0.f};

    for (int k0 = 0; k0 < K; k0 += 32) {
        float4 a0 = *(const float4*)(ap + k0);
        float4 a1 = *(const float4*)(ap + k0 + 4);
        f16x8 av;
        av[0] = (_Float16)a0.x; av[1] = (_Float16)a0.y;
        av[2] = (_Float16)a0.z; av[3] = (_Float16)a0.w;
        av[4] = (_Float16)a1.x; av[5] = (_Float16)a1.y;
        av[6] = (_Float16)a1.z; av[7] = (_Float16)a1.w;
#pragma unroll
        for (int t = 0; t < 6; t++) {
            f16x8 bv = *(const f16x8*)&Wt[t * 16 + c][k0 + (kg << 3)];
            acc[t] = __builtin_amdgcn_mfma_f32_16x16x32_f16(av, bv, acc[t], 0, 0, 0);
        }
    }

    // D -> Hl (fp16): row = 16w + 4*kg + r, col = 16t + c  (static indices)
    int rbase = (w << 4) + (kg << 2);
#pragma unroll
    for (int t = 0; t < 6; t++)
#pragma unroll
        for (int r = 0; r < 4; r++)
            Hl[rbase + r][t * 16 + c] = (_Float16)acc[t][r];
    __syncthreads();

    // epilogue: thread (row=tid>>2, q=tid&3) owns cols [24q,24q+24) = heads 2q,2q+1
    int row = tid >> 2, q = tid & 3;
    int gr = n0 + row;
    if (gr < M) {
        float s0 = 0.f, s1 = 0.f, d0 = 0.f, d1 = 0.f;
#pragma unroll
        for (int j = 0; j < 12; j++) {
            float f = (float)Hl[row][q * 24 + j];
            s0 += f * avl[q * 24 + j];
            d0 += f * adl[q * 24 + j];
        }
#pragma unroll
        for (int j = 12; j < 24; j++) {
            float f = (float)Hl[row][q * 24 + j];
            s1 += f * avl[q * 24 + j];
            d1 += f * adl[q * 24 + j];
        }
        aS[gr * NHEAD + 2 * q]     = s0;
        aS[gr * NHEAD + 2 * q + 1] = s1;
        aD[gr * NHEAD + 2 * q]     = d0;
        aD[gr * NHEAD + 2 * q + 1] = d1;
        const uint4* src = (const uint4*)&Hl[row][q * 24];
        uint4* dst = (uint4*)(Hout + (size_t)gr * D_HID + q * 24);
        dst[0] = src[0]; dst[1] = src[1]; dst[2] = src[2];
    }
}

// ---------------- fused: hist (blocks [0,NHISTB)) + gemm0 (blocks [NHISTB,..)) --------
__global__ __launch_bounds__(256) void hist_gemm_kernel(
    const int* __restrict__ edst, int* __restrict__ cnt,
    const float* __restrict__ A, const _Float16* __restrict__ WT,
    const float* __restrict__ asrc, const float* __restrict__ adst,
    __half* __restrict__ Hout, float* __restrict__ aS, float* __restrict__ aD)
{
    __shared__ _Float16 Wt[D_HID][WPAD];
    __shared__ _Float16 Hl[GBM][104];
    __shared__ float avl[96], adl[96];
    if (blockIdx.x < NHISTB) {
        int lo = (blockIdx.x & 7) * NPART;   // bid&7 == XCD (round-robin dispatch)
        int e0 = (blockIdx.x >> 3) * ECHUNK;
        for (int e = e0 + threadIdx.x; e < e0 + ECHUNK; e += 256) {
            int d = edst[e] - lo;
            if ((unsigned)d < (unsigned)NPART) atomicAdd(&cnt[lo + d], 1);
        }
    } else {
        gemm_alpha_mfma_body(A, WT, asrc, adst, Hout, aS, aD, N_NODES, F_IN,
                             blockIdx.x - NHISTB, Wt, Hl, avl, adl);
    }
}

// ---------------- standalone gemm (layer 1, K=96) ----------------
__global__ __launch_bounds__(256) void gemm_alpha_kernel(
    const float* __restrict__ A, const _Float16* __restrict__ WT,
    const float* __restrict__ asrc, const float* __restrict__ adst,
    __half* __restrict__ Hout, float* __restrict__ aS, float* __restrict__ aD,
    int M, int K)
{
    __shared__ _Float16 Wt[D_HID][WPAD];
    __shared__ _Float16 Hl[GBM][104];
    __shared__ float avl[96], adl[96];
    gemm_alpha_mfma_body(A, WT, asrc, adst, Hout, aS, aD, M, K, blockIdx.x,
                         Wt, Hl, avl, adl);
}

// ---------------- scans ----------------
__global__ void scan1_kernel(const int* __restrict__ cnt, int* __restrict__ incl,
                             int* __restrict__ partials, int n) {
    __shared__ int sdata[256];
    int t = threadIdx.x;
    int base = blockIdx.x * 1024 + t * 4;
    int v[4];
#pragma unroll
    for (int j = 0; j < 4; j++) { int i = base + j; v[j] = (i < n) ? cnt[i] : 0; }
    v[1] += v[0]; v[2] += v[1]; v[3] += v[2];
    sdata[t] = v[3];
    __syncthreads();
    for (int off = 1; off < 256; off <<= 1) {
        int x = (t >= off) ? sdata[t - off] : 0;
        __syncthreads();
        sdata[t] += x;
        __syncthreads();
    }
    int excl = sdata[t] - v[3];
#pragma unroll
    for (int j = 0; j < 4; j++) { int i = base + j; if (i < n) incl[i] = v[j] + excl; }
    if (t == 255) partials[blockIdx.x] = sdata[255];
}

__global__ void scan3_kernel(const int* __restrict__ cnt, int* __restrict__ incl_cursor,
                             const int* __restrict__ partials, int* __restrict__ rowptr,
                             int n, int nb) {
    int i = blockIdx.x * blockDim.x + threadIdx.x;
    if (i >= n) return;
    int myb = i >> 10;
    int psum = 0;
    for (int b = 0; b < nb; b++) psum += (b < myb) ? partials[b] : 0;
    int v = incl_cursor[i] + psum;
    rowptr[i + 1] = v;
    incl_cursor[i] = v - cnt[i];
    if (i == 0) rowptr[0] = 0;
}

__global__ __launch_bounds__(256) void fill_part_kernel(
    const int* __restrict__ esrc, const int* __restrict__ edst,
    int* __restrict__ cursor, unsigned short* __restrict__ srclist)
{
    int lo = (blockIdx.x & 7) * NPART;
    int e0 = (blockIdx.x >> 3) * ECHUNK;
    for (int e = e0 + threadIdx.x; e < e0 + ECHUNK; e += 256) {
        int d = edst[e] - lo;
        if ((unsigned)d < (unsigned)NPART) {
            int p = atomicAdd(&cursor[lo + d], 1);
            srclist[p] = (unsigned short)esrc[e];
        }
    }
}

// ---------------- GAT aggregation: ONE WAVE PER NODE ----------------
// 64 lanes = 8 heads (hh=lane&7) x 8 edge slots (j=lane>>3). Lane (j,hh) walks edges
// s0+j, s0+j+8, ... -> serial chain ~deg/8, 8-16 gathers in flight, exact per-node balance.
// z/acc combined over slots via shfl_xor(8/16/32).
__device__ __forceinline__ void agg_edge(const __half* __restrict__ h, int s, int hh,
                                         float p, float* acc) {
    const uint2* hp = (const uint2*)(h + (size_t)s * D_HID + hh * 12);
    uint2 q0 = hp[0], q1 = hp[1], q2 = hp[2];
    float2 f0 = __half22float2(((const __half2*)&q0)[0]);
    float2 f1 = __half22float2(((const __half2*)&q0)[1]);
    float2 f2 = __half22float2(((const __half2*)&q1)[0]);
    float2 f3 = __half22float2(((const __half2*)&q1)[1]);
    float2 f4 = __half22float2(((const __half2*)&q2)[0]);
    float2 f5 = __half22float2(((const __half2*)&q2)[1]);
    acc[0] += p * f0.x; acc[1]  += p * f0.y;
    acc[2] += p * f1.x; acc[3]  += p * f1.y;
    acc[4] += p * f2.x; acc[5]  += p * f2.y;
    acc[6] += p * f3.x; acc[7]  += p * f3.y;
    acc[8] += p * f4.x; acc[9]  += p * f4.y;
    acc[10] += p * f5.x; acc[11] += p * f5.y;
}

// per-lane slot walk + cross-slot butterfly; returns reduced z, acc valid in all lanes
__device__ __forceinline__ float agg_node_wave(
    const __half* __restrict__ h, const float* __restrict__ aS,
    const unsigned short* __restrict__ srclist,
    int s0, int s1, int j, int hh, float ad, float* acc)
{
    float z = 0.f;
    int i = s0 + j;
    for (; i + 8 < s1; i += 16) {
        int sa = srclist[i];
        int sb = srclist[i + 8];
        float ea = aS[sa * NHEAD + hh] + ad;
        float eb = aS[sb * NHEAD + hh] + ad;
        ea = (ea > 0.f) ? ea : NEG_SLOPE * ea;
        eb = (eb > 0.f) ? eb : NEG_SLOPE * eb;
        float pa = __expf(ea);
        float pb = __expf(eb);
        z += pa + pb;
        agg_edge(h, sa, hh, pa, acc);
        agg_edge(h, sb, hh, pb, acc);
    }
    if (i < s1) {
        int sa = srclist[i];
        float ea = aS[sa * NHEAD + hh] + ad;
        ea = (ea > 0.f) ? ea : NEG_SLOPE * ea;
        float pa = __expf(ea);
        z += pa;
        agg_edge(h, sa, hh, pa, acc);
    }
#pragma unroll
    for (int m = 8; m <= 32; m <<= 1) {
        z += __shfl_xor(z, m, 64);
#pragma unroll
        for (int t = 0; t < 12; t++) acc[t] += __shfl_xor(acc[t], m, 64);
    }
    return z;
}

// layer-0 aggregate -> bufY
__global__ __launch_bounds__(256) void gat_aggregate_kernel(
    const __half* __restrict__ h, const float* __restrict__ aS, const float* __restrict__ aD,
    const int* __restrict__ rowptr, const unsigned short* __restrict__ srclist,
    const float* __restrict__ bias, float* __restrict__ out)
{
    int lane = threadIdx.x & 63;
    int n    = blockIdx.x * 4 + (threadIdx.x >> 6);   // grid exact: 12500*4 = 50000
    int hh   = lane & 7;
    int j    = lane >> 3;
    int s0 = rowptr[n], s1 = rowptr[n + 1];
    float ad = aD[n * NHEAD + hh];

    float acc[12];
#pragma unroll
    for (int t = 0; t < 12; t++) acc[t] = 0.f;
    float z = agg_node_wave(h, aS, srclist, s0, s1, j, hh, ad, acc);

    if (j == 0) {
        float inv = 1.f / (z + 1e-16f);
        const float* bp = bias + hh * 12;
        float o[12];
#pragma unroll
        for (int t = 0; t < 12; t++) o[t] = acc[t] * inv + bp[t];
        float4* op = (float4*)(out + (size_t)n * D_HID + hh * 12);
        op[0] = make_float4(o[0], o[1], o[2], o[3]);
        op[1] = make_float4(o[4], o[5], o[6], o[7]);
        op[2] = make_float4(o[8], o[9], o[10], o[11]);
    }
}

// layer-1 aggregate + relu + (y @ Wout + bout) + log_softmax fused.
// Epilogue: lanes 0-7 publish o[12] to per-wave ylds (same-wave DS, in-order, no barrier);
// lane c<40 computes output column c from fp32 WoutT (global, L1-resident 16KB) with
// y broadcast-read from LDS; softmax via full-wave butterfly with identity padding.
__global__ __launch_bounds__(256) void gat_aggregate_final_kernel(
    const __half* __restrict__ h, const float* __restrict__ aS, const float* __restrict__ aD,
    const int* __restrict__ rowptr, const unsigned short* __restrict__ srclist,
    const float* __restrict__ bias,
    const float* __restrict__ WoT, const float* __restrict__ bout,
    float* __restrict__ out)
{
    __shared__ float ylds[4][D_HID];
    int lane = threadIdx.x & 63;
    int wv   = threadIdx.x >> 6;
    int n    = blockIdx.x * 4 + wv;
    int hh   = lane & 7;
    int j    = lane >> 3;
    int s0 = rowptr[n], s1 = rowptr[n + 1];
    float ad = aD[n * NHEAD + hh];

    float acc[12];
#pragma unroll
    for (int t = 0; t < 12; t++) acc[t] = 0.f;
    float z = agg_node_wave(h, aS, srclist, s0, s1, j, hh, ad, acc);

    if (j == 0) {
        float inv = 1.f / (z + 1e-16f);
        const float* bp = bias + hh * 12;
        float o[12];
#pragma unroll
        for (int t = 0; t < 12; t++) o[t] = fmaxf(acc[t] * inv + bp[t], 0.f);
        float4* yw = (float4*)&ylds[wv][hh * 12];
        yw[0] = make_float4(o[0], o[1], o[2], o[3]);
        yw[1] = make_float4(o[4], o[5], o[6], o[7]);
        yw[2] = make_float4(o[8], o[9], o[10], o[11]);
    }
    // same-wave producer/consumer: DS ops in-order per wave, no barrier needed

    int c = lane;
    float res = 0.f;
    if (c < N_CLS) {
        res = bout[c];
        const float4* wr = (const float4*)(WoT + c * D_HID);
        const float4* yr = (const float4*)&ylds[wv][0];
#pragma unroll
        for (int r4 = 0; r4 < D_HID / 4; r4++) {
            float4 yv = yr[r4];     // broadcast (same addr across lanes)
            float4 wv4 = wr[r4];
            res += yv.x * wv4.x + yv.y * wv4.y + yv.z * wv4.z + yv.w * wv4.w;
        }
    }
    float m = (c < N_CLS) ? res : -3.402823466e+38f;
#pragma unroll
    for (int d = 1; d < 64; d <<= 1) m = fmaxf(m, __shfl_xor(m, d, 64));
    float ev = (c < N_CLS) ? __expf(res - m) : 0.f;
#pragma unroll
    for (int d = 1; d < 64; d <<= 1) ev += __shfl_xor(ev, d, 64);
    float mlg = m + __logf(ev);

    if (c < N_CLS) out[(size_t)n * N_CLS + c] = res - mlg;
}

extern "C" void kernel_launch(void* const* d_in, const int* in_sizes, int n_in,
                              void* d_out, int out_size, void* d_ws, size_t ws_size,
                              hipStream_t stream)
{
    const float* x    = (const float*)d_in[0];
    const int*   esrc = (const int*)d_in[1];
    const int*   edst = (const int*)d_in[2];
    const float* W0   = (const float*)d_in[3];
    const float* as0  = (const float*)d_in[4];
    const float* ad0  = (const float*)d_in[5];
    const float* b0   = (const float*)d_in[6];
    const float* W1   = (const float*)d_in[7];
    const float* as1  = (const float*)d_in[8];
    const float* ad1  = (const float*)d_in[9];
    const float* b1   = (const float*)d_in[10];
    const float* Wout = (const float*)d_in[11];
    const float* bout = (const float*)d_in[12];
    float* out = (float*)d_out;

    char* p = (char*)d_ws;
    float* bufY   = (float*)p; p += (size_t)N_NODES * D_HID * sizeof(float);
    float* aS     = (float*)p; p += (size_t)N_NODES * NHEAD * sizeof(float);
    float* aD     = (float*)p; p += (size_t)N_NODES * NHEAD * sizeof(float);
    __half* bufH  = (__half*)p; p += (size_t)N_NODES * D_HID * sizeof(__half);
    int*   cnt    = (int*)p;   p += ((size_t)N_NODES + 16) * sizeof(int);
    int*   rowptr = (int*)p;   p += ((size_t)N_NODES + 16) * sizeof(int);
    int*   cursor = (int*)p;   p += ((size_t)N_NODES + 16) * sizeof(int);
    unsigned short* srclist = (unsigned short*)p; p += (size_t)N_EDGES * sizeof(unsigned short);
    int*   partials = (int*)p; p += 256;
    _Float16* wt0 = (_Float16*)p; p += (size_t)D_HID * F_IN * sizeof(_Float16);
    _Float16* wt1 = (_Float16*)p; p += (size_t)D_HID * D_HID * sizeof(_Float16);
    float* woutT  = (float*)p;  p += (size_t)N_CLS * D_HID * sizeof(float);

    int nscan = (N_NODES + 1023) / 1024;   // 49

    // 1. zero cnt + transpose/convert W0/W1/Wout (one dispatch, grid-sliced)
    pre_kernel<<<148, 256, 0, stream>>>((int4*)cnt, W0, W1, Wout, wt0, wt1, woutT);
    // 2. hist (XCD-partitioned) + MFMA gemm0 fused by grid-slicing
    hist_gemm_kernel<<<NHISTB + NGB, 256, 0, stream>>>(
        edst, cnt, x, wt0, as0, ad0, bufH, aS, aD);
    // 3-4. scan
    scan1_kernel<<<nscan, 256, 0, stream>>>(cnt, cursor, partials, N_NODES);
    scan3_kernel<<<(N_NODES + 255) / 256, 256, 0, stream>>>(cnt, cursor, partials, rowptr,
                                                            N_NODES, nscan);
    // 5. fill CSR
    fill_part_kernel<<<NHISTB, 256, 0, stream>>>(esrc, edst, cursor, srclist);
    // 6. layer-0 aggregate -> bufY (one wave per node)
    gat_aggregate_kernel<<<N_NODES / 4, 256, 0, stream>>>(
        bufH, aS, aD, rowptr, srclist, b0, bufY);
    // 7. layer-1 MFMA gemm (K=96)
    gemm_alpha_kernel<<<NGB, 256, 0, stream>>>(
        bufY, wt1, as1, ad1, bufH, aS, aD, N_NODES, D_HID);
    // 8. layer-1 aggregate + relu + output linear + log_softmax -> out
    gat_aggregate_final_kernel<<<N_NODES / 4, 256, 0, stream>>>(
        bufH, aS, aD, rowptr, srclist, b1, woutT, bout, out);
}

// Round 10
// 231.381 us; speedup vs baseline: 1.1380x; 1.1380x over previous
//
#include <hip/hip_runtime.h>
#include <hip/hip_fp16.h>
#include <math.h>

#define N_NODES 50000
#define N_EDGES 800000
#define F_IN    128
#define D_HID   96
#define NHEAD   8
#define DH      12
#define N_CLS   40
#define NEG_SLOPE 0.2f

#define NPART   (N_NODES / 8)        // 6250 dst nodes per XCD group
#define NWCHUNK 256                  // edge chunks per group
#define ECHUNK  (N_EDGES / NWCHUNK)  // 3125 edges per chunk
#define NHISTB  (8 * NWCHUNK)        // 2048 hist/fill blocks

#define GBM 64                       // gemm rows per block
#define NGB ((N_NODES + GBM - 1) / GBM)   // 782
#define WPAD 136                     // LDS W row pad (272B: 16B aligned, 2-way banks = free)

#define HALFN   (N_NODES / 2)        // 25000
#define AGG_NPB 64                   // nodes per aggregate block (256 thr / 4 lanes)
#define NAGGB   ((HALFN + AGG_NPB - 1) / AGG_NPB)   // 391

typedef _Float16 f16x8 __attribute__((ext_vector_type(8)));
typedef float    f32x4 __attribute__((ext_vector_type(4)));

// ---------------- pre: zero cnt + fp16-transpose W0/W1 ----------------
__global__ __launch_bounds__(256) void pre_kernel(
    int4* __restrict__ cnt4, const float* __restrict__ W0, const float* __restrict__ W1,
    _Float16* __restrict__ wt0, _Float16* __restrict__ wt1)
{
    int b = blockIdx.x, t = threadIdx.x;
    if (b < 49) {
        int i = b * 256 + t;
        if (i < 12504) cnt4[i] = make_int4(0, 0, 0, 0);
    } else if (b < 97) {
        int idx = (b - 49) * 256 + t;          // idx = n*128+k (write-coalesced)
        int n = idx >> 7, k = idx & 127;
        wt0[idx] = (_Float16)W0[k * D_HID + n];
    } else {
        int idx = (b - 97) * 256 + t;          // idx = n*96+k
        int n = idx / 96, k = idx - n * 96;
        wt1[idx] = (_Float16)W1[k * D_HID + n];
    }
}

// ---------------- MFMA GEMM core: H = A[M,K] @ W[K,96] (fp16 in, fp32 acc) ------------
// Wave w: rows [bid*64+16w,+16) x 96 cols via 6 x mfma_f32_16x16x32_f16 (layout verified
// r7/m89). W staged once; A-fragments straight from global. Epilogue writes the
// QUARTER-TABLE layout: hq[q][node][24] fp16 (heads 2q,2q+1), aSq/aDq[q][node][2] fp32.
__device__ __forceinline__ void gemm_alpha_mfma_body(
    const float* __restrict__ A, const _Float16* __restrict__ WT,
    const float* __restrict__ asrc, const float* __restrict__ adst,
    __half* __restrict__ Hq, float* __restrict__ aSq, float* __restrict__ aDq,
    int M, int K, int bid,
    _Float16 (*Wt)[WPAD], _Float16 (*Hl)[104], float* avl, float* adl)
{
    int tid  = threadIdx.x;
    int lane = tid & 63;
    int w    = tid >> 6;
    int n0   = bid * GBM;

    int cpr = K >> 3;
    int nch = 96 * cpr;
    for (int ch = tid; ch < nch; ch += 256) {
        int row = ch / cpr, off = (ch - row * cpr) << 3;
        *(f16x8*)&Wt[row][off] = *(const f16x8*)&WT[row * K + off];
    }
    if (tid < 96) { avl[tid] = asrc[tid]; adl[tid] = adst[tid]; }
    __syncthreads();

    int c  = lane & 15;
    int kg = lane >> 4;
    int arow = n0 + (w << 4) + c;
    const float* ap = A + (size_t)(arow < M ? arow : M - 1) * K + (kg << 3);

    f32x4 acc[6];
#pragma unroll
    for (int t = 0; t < 6; t++) acc[t] = (f32x4){0.f, 0.f, 0.f, 0.f};

    for (int k0 = 0; k0 < K; k0 += 32) {
        float4 a0 = *(const float4*)(ap + k0);
        float4 a1 = *(const float4*)(ap + k0 + 4);
        f16x8 av;
        av[0] = (_Float16)a0.x; av[1] = (_Float16)a0.y;
        av[2] = (_Float16)a0.z; av[3] = (_Float16)a0.w;
        av[4] = (_Float16)a1.x; av[5] = (_Float16)a1.y;
        av[6] = (_Float16)a1.z; av[7] = (_Float16)a1.w;
#pragma unroll
        for (int t = 0; t < 6; t++) {
            f16x8 bv = *(const f16x8*)&Wt[t * 16 + c][k0 + (kg << 3)];
            acc[t] = __builtin_amdgcn_mfma_f32_16x16x32_f16(av, bv, acc[t], 0, 0, 0);
        }
    }

    int rbase = (w << 4) + (kg << 2);
#pragma unroll
    for (int t = 0; t < 6; t++)
#pragma unroll
        for (int r = 0; r < 4; r++)
            Hl[rbase + r][t * 16 + c] = (_Float16)acc[t][r];
    __syncthreads();

    // epilogue: thread (row=tid>>2, q=tid&3) owns cols [24q,24q+24) = group q
    int row = tid >> 2, q = tid & 3;
    int gr = n0 + row;
    if (gr < M) {
        float s0 = 0.f, s1 = 0.f, d0 = 0.f, d1 = 0.f;
#pragma unroll
        for (int j = 0; j < 12; j++) {
            float f = (float)Hl[row][q * 24 + j];
            s0 += f * avl[q * 24 + j];
            d0 += f * adl[q * 24 + j];
        }
#pragma unroll
        for (int j = 12; j < 24; j++) {
            float f = (float)Hl[row][q * 24 + j];
            s1 += f * avl[q * 24 + j];
            d1 += f * adl[q * 24 + j];
        }
        float* aSg = aSq + (size_t)q * N_NODES * 2;
        float* aDg = aDq + (size_t)q * N_NODES * 2;
        aSg[gr * 2]     = s0;  aSg[gr * 2 + 1] = s1;
        aDg[gr * 2]     = d0;  aDg[gr * 2 + 1] = d1;
        const uint4* src = (const uint4*)&Hl[row][q * 24];
        uint4* dst = (uint4*)(Hq + (size_t)q * N_NODES * 24 + (size_t)gr * 24);
        dst[0] = src[0]; dst[1] = src[1]; dst[2] = src[2];
    }
}

// ---------------- fused: hist (blocks [0,NHISTB)) + gemm0 (blocks [NHISTB,..)) --------
__global__ __launch_bounds__(256) void hist_gemm_kernel(
    const int* __restrict__ edst, int* __restrict__ cnt,
    const float* __restrict__ A, const _Float16* __restrict__ WT,
    const float* __restrict__ asrc, const float* __restrict__ adst,
    __half* __restrict__ Hq, float* __restrict__ aSq, float* __restrict__ aDq)
{
    __shared__ _Float16 Wt[D_HID][WPAD];
    __shared__ _Float16 Hl[GBM][104];
    __shared__ float avl[96], adl[96];
    if (blockIdx.x < NHISTB) {
        int lo = (blockIdx.x & 7) * NPART;   // bid&7 == XCD (round-robin dispatch)
        int e0 = (blockIdx.x >> 3) * ECHUNK;
        for (int e = e0 + threadIdx.x; e < e0 + ECHUNK; e += 256) {
            int d = edst[e] - lo;
            if ((unsigned)d < (unsigned)NPART) atomicAdd(&cnt[lo + d], 1);
        }
    } else {
        gemm_alpha_mfma_body(A, WT, asrc, adst, Hq, aSq, aDq, N_NODES, F_IN,
                             blockIdx.x - NHISTB, Wt, Hl, avl, adl);
    }
}

__global__ __launch_bounds__(256) void gemm_alpha_kernel(
    const float* __restrict__ A, const _Float16* __restrict__ WT,
    const float* __restrict__ asrc, const float* __restrict__ adst,
    __half* __restrict__ Hq, float* __restrict__ aSq, float* __restrict__ aDq,
    int M, int K)
{
    __shared__ _Float16 Wt[D_HID][WPAD];
    __shared__ _Float16 Hl[GBM][104];
    __shared__ float avl[96], adl[96];
    gemm_alpha_mfma_body(A, WT, asrc, adst, Hq, aSq, aDq, M, K, blockIdx.x,
                         Wt, Hl, avl, adl);
}

// ---------------- scans ----------------
__global__ void scan1_kernel(const int* __restrict__ cnt, int* __restrict__ incl,
                             int* __restrict__ partials, int n) {
    __shared__ int sdata[256];
    int t = threadIdx.x;
    int base = blockIdx.x * 1024 + t * 4;
    int v[4];
#pragma unroll
    for (int j = 0; j < 4; j++) { int i = base + j; v[j] = (i < n) ? cnt[i] : 0; }
    v[1] += v[0]; v[2] += v[1]; v[3] += v[2];
    sdata[t] = v[3];
    __syncthreads();
    for (int off = 1; off < 256; off <<= 1) {
        int x = (t >= off) ? sdata[t - off] : 0;
        __syncthreads();
        sdata[t] += x;
        __syncthreads();
    }
    int excl = sdata[t] - v[3];
#pragma unroll
    for (int j = 0; j < 4; j++) { int i = base + j; if (i < n) incl[i] = v[j] + excl; }
    if (t == 255) partials[blockIdx.x] = sdata[255];
}

__global__ void scan3_kernel(const int* __restrict__ cnt, int* __restrict__ incl_cursor,
                             const int* __restrict__ partials, int* __restrict__ rowptr,
                             int n, int nb) {
    int i = blockIdx.x * blockDim.x + threadIdx.x;
    if (i >= n) return;
    int myb = i >> 10;
    int psum = 0;
    for (int b = 0; b < nb; b++) psum += (b < myb) ? partials[b] : 0;
    int v = incl_cursor[i] + psum;
    rowptr[i + 1] = v;
    incl_cursor[i] = v - cnt[i];
    if (i == 0) rowptr[0] = 0;
}

__global__ __launch_bounds__(256) void fill_part_kernel(
    const int* __restrict__ esrc, const int* __restrict__ edst,
    int* __restrict__ cursor, unsigned short* __restrict__ srclist)
{
    int lo = (blockIdx.x & 7) * NPART;
    int e0 = (blockIdx.x >> 3) * ECHUNK;
    for (int e = e0 + threadIdx.x; e < e0 + ECHUNK; e += 256) {
        int d = edst[e] - lo;
        if ((unsigned)d < (unsigned)NPART) {
            int p = atomicAdd(&cursor[lo + d], 1);
            srclist[p] = (unsigned short)esrc[e];
        }
    }
}

// ---------------- GAT aggregation: quarter-table, XCD-partitioned ----------------
// grid = 8*NAGGB. slot s=bid&7: head-group g=s>>1 (heads 2g,2g+1), node-half=s&1.
// Each XCD slot gathers from ONE 2.4MB quarter-table -> fits per-XCD L2.
// 4 lanes/node: l=tid&3, hh2=l&1, slot j=l>>1; lane walks deg/2 edges stride 2,
// 4-wide unroll (r8-proven shape); combine via one shfl_xor(2).
__device__ __forceinline__ void agg_edge_q(const __half* __restrict__ hq, int sa, int hh2,
                                           float p, float* acc) {
    const uint2* hp = (const uint2*)(hq + (size_t)sa * 24 + hh2 * 12);
    uint2 q0 = hp[0], q1 = hp[1], q2 = hp[2];
    float2 f0 = __half22float2(((const __half2*)&q0)[0]);
    float2 f1 = __half22float2(((const __half2*)&q0)[1]);
    float2 f2 = __half22float2(((const __half2*)&q1)[0]);
    float2 f3 = __half22float2(((const __half2*)&q1)[1]);
    float2 f4 = __half22float2(((const __half2*)&q2)[0]);
    float2 f5 = __half22float2(((const __half2*)&q2)[1]);
    acc[0] += p * f0.x; acc[1]  += p * f0.y;
    acc[2] += p * f1.x; acc[3]  += p * f1.y;
    acc[4] += p * f2.x; acc[5]  += p * f2.y;
    acc[6] += p * f3.x; acc[7]  += p * f3.y;
    acc[8] += p * f4.x; acc[9]  += p * f4.y;
    acc[10] += p * f5.x; acc[11] += p * f5.y;
}

__global__ __launch_bounds__(256) void gat_aggregate_q_kernel(
    const __half* __restrict__ Hq, const float* __restrict__ aSq,
    const float* __restrict__ aDq,
    const int* __restrict__ rowptr, const unsigned short* __restrict__ srclist,
    const float* __restrict__ bias, float* __restrict__ outY, int relu)
{
    int s    = blockIdx.x & 7;
    int g    = s >> 1;
    int half = s & 1;
    int local = (blockIdx.x >> 3) * AGG_NPB + (threadIdx.x >> 2);
    if (local >= HALFN) return;
    int n   = half * HALFN + local;
    int l   = threadIdx.x & 3;
    int hh2 = l & 1;
    int j   = l >> 1;

    const __half* hq  = Hq + (size_t)g * N_NODES * 24;
    const float*  aSg = aSq + (size_t)g * N_NODES * 2;
    float ad = aDq[(size_t)g * N_NODES * 2 + n * 2 + hh2];

    int s0 = rowptr[n], s1 = rowptr[n + 1];
    float z = 0.f;
    float acc[12];
#pragma unroll
    for (int t = 0; t < 12; t++) acc[t] = 0.f;

    int i = s0 + j;
    for (; i + 6 < s1; i += 8) {
        int sa = srclist[i];
        int sb = srclist[i + 2];
        int sc = srclist[i + 4];
        int sd = srclist[i + 6];
        float ea = aSg[sa * 2 + hh2] + ad;
        float eb = aSg[sb * 2 + hh2] + ad;
        float ec = aSg[sc * 2 + hh2] + ad;
        float ed = aSg[sd * 2 + hh2] + ad;
        ea = (ea > 0.f) ? ea : NEG_SLOPE * ea;
        eb = (eb > 0.f) ? eb : NEG_SLOPE * eb;
        ec = (ec > 0.f) ? ec : NEG_SLOPE * ec;
        ed = (ed > 0.f) ? ed : NEG_SLOPE * ed;
        float pa = __expf(ea);
        float pb = __expf(eb);
        float pc = __expf(ec);
        float pd = __expf(ed);
        z += (pa + pb) + (pc + pd);
        agg_edge_q(hq, sa, hh2, pa, acc);
        agg_edge_q(hq, sb, hh2, pb, acc);
        agg_edge_q(hq, sc, hh2, pc, acc);
        agg_edge_q(hq, sd, hh2, pd, acc);
    }
    for (; i < s1; i += 2) {
        int sa = srclist[i];
        float ea = aSg[sa * 2 + hh2] + ad;
        ea = (ea > 0.f) ? ea : NEG_SLOPE * ea;
        float pa = __expf(ea);
        z += pa;
        agg_edge_q(hq, sa, hh2, pa, acc);
    }

    // combine the two slots (lanes l and l^2 share node+head)
    z += __shfl_xor(z, 2, 64);
#pragma unroll
    for (int t = 0; t < 12; t++) acc[t] += __shfl_xor(acc[t], 2, 64);

    if (j == 0) {
        float inv = 1.f / (z + 1e-16f);
        const float* bp = bias + g * 24 + hh2 * 12;
        float o[12];
#pragma unroll
        for (int t = 0; t < 12; t++) o[t] = acc[t] * inv + bp[t];
        if (relu) {
#pragma unroll
            for (int t = 0; t < 12; t++) o[t] = fmaxf(o[t], 0.f);
        }
        float4* op = (float4*)(outY + (size_t)n * D_HID + g * 24 + hh2 * 12);
        op[0] = make_float4(o[0], o[1], o[2], o[3]);
        op[1] = make_float4(o[4], o[5], o[6], o[7]);
        op[2] = make_float4(o[8], o[9], o[10], o[11]);
    }
}

// ---------------- final linear (96->40) + bias + log_softmax, thread per node --------
__global__ __launch_bounds__(256) void out_lsm_kernel(
    const float* __restrict__ X, const float* __restrict__ Wout,
    const float* __restrict__ bout, float* __restrict__ out)
{
    __shared__ float Ws[D_HID * N_CLS];
    __shared__ float bs[N_CLS];
    for (int i = threadIdx.x; i < D_HID * N_CLS; i += 256) Ws[i] = Wout[i];
    for (int i = threadIdx.x; i < N_CLS; i += 256) bs[i] = bout[i];
    __syncthreads();

    int n = blockIdx.x * blockDim.x + threadIdx.x;
    if (n >= N_NODES) return;

    float acc[N_CLS];
#pragma unroll
    for (int c = 0; c < N_CLS; c++) acc[c] = bs[c];

    const float4* xp = (const float4*)(X + (size_t)n * D_HID);
    for (int k4 = 0; k4 < D_HID / 4; k4++) {
        float4 xv = xp[k4];
        const float* wrow = &Ws[(k4 * 4) * N_CLS];
#pragma unroll
        for (int c4 = 0; c4 < N_CLS / 4; c4++) {
            float4 wa = *(const float4*)(wrow + c4 * 4);
            float4 wb = *(const float4*)(wrow + N_CLS + c4 * 4);
            float4 wc = *(const float4*)(wrow + 2 * N_CLS + c4 * 4);
            float4 wd = *(const float4*)(wrow + 3 * N_CLS + c4 * 4);
            acc[c4 * 4 + 0] += xv.x * wa.x + xv.y * wb.x + xv.z * wc.x + xv.w * wd.x;
            acc[c4 * 4 + 1] += xv.x * wa.y + xv.y * wb.y + xv.z * wc.y + xv.w * wd.y;
            acc[c4 * 4 + 2] += xv.x * wa.z + xv.y * wb.z + xv.z * wc.z + xv.w * wd.z;
            acc[c4 * 4 + 3] += xv.x * wa.w + xv.y * wb.w + xv.z * wc.w + xv.w * wd.w;
        }
    }

    float m = acc[0];
#pragma unroll
    for (int c = 1; c < N_CLS; c++) m = fmaxf(m, acc[c]);
    float s = 0.f;
#pragma unroll
    for (int c = 0; c < N_CLS; c++) s += __expf(acc[c] - m);
    float lg = __logf(s);

    float4* op = (float4*)(out + (size_t)n * N_CLS);
#pragma unroll
    for (int c4 = 0; c4 < N_CLS / 4; c4++) {
        op[c4] = make_float4(acc[c4 * 4 + 0] - m - lg, acc[c4 * 4 + 1] - m - lg,
                             acc[c4 * 4 + 2] - m - lg, acc[c4 * 4 + 3] - m - lg);
    }
}

extern "C" void kernel_launch(void* const* d_in, const int* in_sizes, int n_in,
                              void* d_out, int out_size, void* d_ws, size_t ws_size,
                              hipStream_t stream)
{
    const float* x    = (const float*)d_in[0];
    const int*   esrc = (const int*)d_in[1];
    const int*   edst = (const int*)d_in[2];
    const float* W0   = (const float*)d_in[3];
    const float* as0  = (const float*)d_in[4];
    const float* ad0  = (const float*)d_in[5];
    const float* b0   = (const float*)d_in[6];
    const float* W1   = (const float*)d_in[7];
    const float* as1  = (const float*)d_in[8];
    const float* ad1  = (const float*)d_in[9];
    const float* b1   = (const float*)d_in[10];
    const float* Wout = (const float*)d_in[11];
    const float* bout = (const float*)d_in[12];
    float* out = (float*)d_out;

    char* p = (char*)d_ws;
    float* bufY   = (float*)p; p += (size_t)N_NODES * D_HID * sizeof(float);
    float* aSq    = (float*)p; p += (size_t)N_NODES * NHEAD * sizeof(float);
    float* aDq    = (float*)p; p += (size_t)N_NODES * NHEAD * sizeof(float);
    __half* Hq    = (__half*)p; p += (size_t)N_NODES * D_HID * sizeof(__half);
    int*   cnt    = (int*)p;   p += ((size_t)N_NODES + 16) * sizeof(int);
    int*   rowptr = (int*)p;   p += ((size_t)N_NODES + 16) * sizeof(int);
    int*   cursor = (int*)p;   p += ((size_t)N_NODES + 16) * sizeof(int);
    unsigned short* srclist = (unsigned short*)p; p += (size_t)N_EDGES * sizeof(unsigned short);
    int*   partials = (int*)p; p += 256;
    _Float16* wt0 = (_Float16*)p; p += (size_t)D_HID * F_IN * sizeof(_Float16);
    _Float16* wt1 = (_Float16*)p; p += (size_t)D_HID * D_HID * sizeof(_Float16);

    int nscan = (N_NODES + 1023) / 1024;   // 49

    // 1. zero cnt + fp16-transpose W0/W1
    pre_kernel<<<133, 256, 0, stream>>>((int4*)cnt, W0, W1, wt0, wt1);
    // 2. hist (XCD-partitioned) + MFMA gemm0 (quarter-table epilogue)
    hist_gemm_kernel<<<NHISTB + NGB, 256, 0, stream>>>(
        edst, cnt, x, wt0, as0, ad0, Hq, aSq, aDq);
    // 3-4. scan
    scan1_kernel<<<nscan, 256, 0, stream>>>(cnt, cursor, partials, N_NODES);
    scan3_kernel<<<(N_NODES + 255) / 256, 256, 0, stream>>>(cnt, cursor, partials, rowptr,
                                                            N_NODES, nscan);
    // 5. fill CSR
    fill_part_kernel<<<NHISTB, 256, 0, stream>>>(esrc, edst, cursor, srclist);
    // 6. layer-0 aggregate (XCD-partitioned quarter gather) -> bufY
    gat_aggregate_q_kernel<<<8 * NAGGB, 256, 0, stream>>>(
        Hq, aSq, aDq, rowptr, srclist, b0, bufY, 0);
    // 7. layer-1 MFMA gemm (K=96)
    gemm_alpha_kernel<<<NGB, 256, 0, stream>>>(
        bufY, wt1, as1, ad1, Hq, aSq, aDq, N_NODES, D_HID);
    // 8. layer-1 aggregate + relu -> bufY
    gat_aggregate_q_kernel<<<8 * NAGGB, 256, 0, stream>>>(
        Hq, aSq, aDq, rowptr, srclist, b1, bufY, 1);
    // 9. output linear + log_softmax
    out_lsm_kernel<<<(N_NODES + 255) / 256, 256, 0, stream>>>(bufY, Wout, bout, out);
}

// Round 11
// 205.761 us; speedup vs baseline: 1.2797x; 1.1245x over previous
//
#include <hip/hip_runtime.h>
#include <hip/hip_fp16.h>
#include <math.h>

#define N_NODES 50000
#define N_EDGES 800000
#define F_IN    128
#define D_HID   96
#define NHEAD   8
#define DH      12
#define N_CLS   40
#define NEG_SLOPE 0.2f

#define NPART   (N_NODES / 8)        // 6250 dst nodes per XCD group
#define NWCHUNK 250                  // edge chunks per group
#define ECHUNK  (N_EDGES / NWCHUNK)  // 3200 edges per chunk (divisible by 4: int4 loads)
#define NHISTB  (8 * NWCHUNK)        // 2000 hist/fill blocks

#define GBM 64                       // gemm rows per block
#define NGB ((N_NODES + GBM - 1) / GBM)   // 782
#define WPAD 136                     // LDS W row pad (272B: 16B aligned, 2-way banks = free)

#define HALFN   (N_NODES / 2)        // 25000
#define AGG_NPB 32                   // nodes per aggregate block (256 thr / 8 lanes)
#define NAGGB   ((HALFN + AGG_NPB - 1) / AGG_NPB)   // 782

typedef _Float16 f16x8 __attribute__((ext_vector_type(8)));
typedef float    f32x4 __attribute__((ext_vector_type(4)));

// ---------------- pre: zero cnt + fp16-transpose W0/W1 ----------------
__global__ __launch_bounds__(256) void pre_kernel(
    int4* __restrict__ cnt4, const float* __restrict__ W0, const float* __restrict__ W1,
    _Float16* __restrict__ wt0, _Float16* __restrict__ wt1)
{
    int b = blockIdx.x, t = threadIdx.x;
    if (b < 49) {
        int i = b * 256 + t;
        if (i < 12504) cnt4[i] = make_int4(0, 0, 0, 0);
    } else if (b < 97) {
        int idx = (b - 49) * 256 + t;          // idx = n*128+k (write-coalesced)
        int n = idx >> 7, k = idx & 127;
        wt0[idx] = (_Float16)W0[k * D_HID + n];
    } else {
        int idx = (b - 97) * 256 + t;          // idx = n*96+k
        int n = idx / 96, k = idx - n * 96;
        wt1[idx] = (_Float16)W1[k * D_HID + n];
    }
}

// ---------------- MFMA GEMM core: H = A[M,K] @ W[K,96] (fp16 in, fp32 acc) ------------
// Wave w: rows [bid*64+16w,+16) x 96 cols via 6 x mfma_f32_16x16x32_f16 (layout verified
// r7/m89). Epilogue packs PER-GROUP 64B RECORDS: group q, node n:
//   [aS_2q (f32) | h cols 0..5][h cols 6..11 | aD_2q] [aS_2q+1 | h 12..17][h 18..23 | aD_2q+1]
// so the aggregate reads ONE cache line per (edge, group).
template<bool A16>
__device__ __forceinline__ void gemm_alpha_mfma_body(
    const void* __restrict__ Av, const _Float16* __restrict__ WT,
    const float* __restrict__ asrc, const float* __restrict__ adst,
    uint4* __restrict__ Hrec,
    int M, int K, int bid,
    _Float16 (*Wt)[WPAD], _Float16 (*Hl)[104], float* avl, float* adl)
{
    int tid  = threadIdx.x;
    int lane = tid & 63;
    int w    = tid >> 6;
    int n0   = bid * GBM;

    int cpr = K >> 3;
    int nch = 96 * cpr;
    for (int ch = tid; ch < nch; ch += 256) {
        int row = ch / cpr, off = (ch - row * cpr) << 3;
        *(f16x8*)&Wt[row][off] = *(const f16x8*)&WT[row * K + off];
    }
    if (tid < 96) { avl[tid] = asrc[tid]; adl[tid] = adst[tid]; }
    __syncthreads();

    int c  = lane & 15;
    int kg = lane >> 4;
    int arow = n0 + (w << 4) + c;
    int ar = arow < M ? arow : M - 1;

    f32x4 acc[6];
#pragma unroll
    for (int t = 0; t < 6; t++) acc[t] = (f32x4){0.f, 0.f, 0.f, 0.f};

    for (int k0 = 0; k0 < K; k0 += 32) {
        f16x8 av;
        if constexpr (A16) {
            const _Float16* ap = (const _Float16*)Av + (size_t)ar * K + (kg << 3);
            av = *(const f16x8*)(ap + k0);
        } else {
            const float* ap = (const float*)Av + (size_t)ar * K + (kg << 3);
            float4 a0 = *(const float4*)(ap + k0);
            float4 a1 = *(const float4*)(ap + k0 + 4);
            av[0] = (_Float16)a0.x; av[1] = (_Float16)a0.y;
            av[2] = (_Float16)a0.z; av[3] = (_Float16)a0.w;
            av[4] = (_Float16)a1.x; av[5] = (_Float16)a1.y;
            av[6] = (_Float16)a1.z; av[7] = (_Float16)a1.w;
        }
#pragma unroll
        for (int t = 0; t < 6; t++) {
            f16x8 bv = *(const f16x8*)&Wt[t * 16 + c][k0 + (kg << 3)];
            acc[t] = __builtin_amdgcn_mfma_f32_16x16x32_f16(av, bv, acc[t], 0, 0, 0);
        }
    }

    int rbase = (w << 4) + (kg << 2);
#pragma unroll
    for (int t = 0; t < 6; t++)
#pragma unroll
        for (int r = 0; r < 4; r++)
            Hl[rbase + r][t * 16 + c] = (_Float16)acc[t][r];
    __syncthreads();

    // epilogue: thread (row=tid>>2, q=tid&3) owns cols [24q,24q+24) = heads 2q,2q+1
    int row = tid >> 2, q = tid & 3;
    int gr = n0 + row;
    if (gr < M) {
        float s0 = 0.f, s1 = 0.f, d0 = 0.f, d1 = 0.f;
#pragma unroll
        for (int j = 0; j < 12; j++) {
            float f = (float)Hl[row][q * 24 + j];
            s0 += f * avl[q * 24 + j];
            d0 += f * adl[q * 24 + j];
        }
#pragma unroll
        for (int j = 12; j < 24; j++) {
            float f = (float)Hl[row][q * 24 + j];
            s1 += f * avl[q * 24 + j];
            d1 += f * adl[q * 24 + j];
        }
        const uint* hp = (const uint*)&Hl[row][q * 24];   // 12 uints = 24 halfs
        uint4* rec = Hrec + ((size_t)q * N_NODES + gr) * 4;
        rec[0] = make_uint4(__float_as_uint(s0), hp[0], hp[1], hp[2]);
        rec[1] = make_uint4(hp[3], hp[4], hp[5], __float_as_uint(d0));
        rec[2] = make_uint4(__float_as_uint(s1), hp[6], hp[7], hp[8]);
        rec[3] = make_uint4(hp[9], hp[10], hp[11], __float_as_uint(d1));
    }
}

// ---------------- fused: hist (blocks [0,NHISTB)) + gemm0 (blocks [NHISTB,..)) --------
__global__ __launch_bounds__(256) void hist_gemm_kernel(
    const int* __restrict__ edst, int* __restrict__ cnt,
    const float* __restrict__ A, const _Float16* __restrict__ WT,
    const float* __restrict__ asrc, const float* __restrict__ adst,
    uint4* __restrict__ Hrec)
{
    __shared__ _Float16 Wt[D_HID][WPAD];
    __shared__ _Float16 Hl[GBM][104];
    __shared__ float avl[96], adl[96];
    if (blockIdx.x < NHISTB) {
        int lo = (blockIdx.x & 7) * NPART;   // bid&7 == XCD (round-robin dispatch)
        const int4* d4 = (const int4*)(edst + (blockIdx.x >> 3) * ECHUNK);
        for (int c = threadIdx.x; c < ECHUNK / 4; c += 256) {
            int4 dv = d4[c];
            int a = dv.x - lo, b = dv.y - lo, cc = dv.z - lo, dd = dv.w - lo;
            if ((unsigned)a  < (unsigned)NPART) atomicAdd(&cnt[lo + a], 1);
            if ((unsigned)b  < (unsigned)NPART) atomicAdd(&cnt[lo + b], 1);
            if ((unsigned)cc < (unsigned)NPART) atomicAdd(&cnt[lo + cc], 1);
            if ((unsigned)dd < (unsigned)NPART) atomicAdd(&cnt[lo + dd], 1);
        }
    } else {
        gemm_alpha_mfma_body<false>(A, WT, asrc, adst, Hrec, N_NODES, F_IN,
                                    blockIdx.x - NHISTB, Wt, Hl, avl, adl);
    }
}

// ---------------- standalone gemm (layer 1, fp16 A, K=96) ----------------
__global__ __launch_bounds__(256) void gemm_alpha_kernel(
    const _Float16* __restrict__ A, const _Float16* __restrict__ WT,
    const float* __restrict__ asrc, const float* __restrict__ adst,
    uint4* __restrict__ Hrec, int M, int K)
{
    __shared__ _Float16 Wt[D_HID][WPAD];
    __shared__ _Float16 Hl[GBM][104];
    __shared__ float avl[96], adl[96];
    gemm_alpha_mfma_body<true>(A, WT, asrc, adst, Hrec, M, K, blockIdx.x,
                               Wt, Hl, avl, adl);
}

// ---------------- scans ----------------
__global__ void scan1_kernel(const int* __restrict__ cnt, int* __restrict__ incl,
                             int* __restrict__ partials, int n) {
    __shared__ int sdata[256];
    int t = threadIdx.x;
    int base = blockIdx.x * 1024 + t * 4;
    int v[4];
#pragma unroll
    for (int j = 0; j < 4; j++) { int i = base + j; v[j] = (i < n) ? cnt[i] : 0; }
    v[1] += v[0]; v[2] += v[1]; v[3] += v[2];
    sdata[t] = v[3];
    __syncthreads();
    for (int off = 1; off < 256; off <<= 1) {
        int x = (t >= off) ? sdata[t - off] : 0;
        __syncthreads();
        sdata[t] += x;
        __syncthreads();
    }
    int excl = sdata[t] - v[3];
#pragma unroll
    for (int j = 0; j < 4; j++) { int i = base + j; if (i < n) incl[i] = v[j] + excl; }
    if (t == 255) partials[blockIdx.x] = sdata[255];
}

__global__ void scan3_kernel(const int* __restrict__ cnt, int* __restrict__ incl_cursor,
                             const int* __restrict__ partials, int* __restrict__ rowptr,
                             int n, int nb) {
    int i = blockIdx.x * blockDim.x + threadIdx.x;
    if (i >= n) return;
    int myb = i >> 10;
    int psum = 0;
    for (int b = 0; b < nb; b++) psum += (b < myb) ? partials[b] : 0;
    int v = incl_cursor[i] + psum;
    rowptr[i + 1] = v;
    incl_cursor[i] = v - cnt[i];
    if (i == 0) rowptr[0] = 0;
}

__global__ __launch_bounds__(256) void fill_part_kernel(
    const int* __restrict__ esrc, const int* __restrict__ edst,
    int* __restrict__ cursor, unsigned short* __restrict__ srclist)
{
    int lo = (blockIdx.x & 7) * NPART;
    int ebase = (blockIdx.x >> 3) * ECHUNK;
    const int4* d4 = (const int4*)(edst + ebase);
    for (int c = threadIdx.x; c < ECHUNK / 4; c += 256) {
        int4 dv = d4[c];
        int e = ebase + c * 4;
        int a = dv.x - lo, b = dv.y - lo, cc = dv.z - lo, dd = dv.w - lo;
        if ((unsigned)a < (unsigned)NPART) {
            int p = atomicAdd(&cursor[lo + a], 1); srclist[p] = (unsigned short)esrc[e];
        }
        if ((unsigned)b < (unsigned)NPART) {
            int p = atomicAdd(&cursor[lo + b], 1); srclist[p] = (unsigned short)esrc[e + 1];
        }
        if ((unsigned)cc < (unsigned)NPART) {
            int p = atomicAdd(&cursor[lo + cc], 1); srclist[p] = (unsigned short)esrc[e + 2];
        }
        if ((unsigned)dd < (unsigned)NPART) {
            int p = atomicAdd(&cursor[lo + dd], 1); srclist[p] = (unsigned short)esrc[e + 3];
        }
    }
}

// ---------------- GAT aggregation: packed records, XCD-partitioned ----------------
// grid = 8*NAGGB. slot s=bid&7: head-group g=s>>1 (heads 2g,2g+1), node-half=s&1.
// Each XCD slot gathers from ONE 3.2MB record table -> fits per-XCD L2.
// 8 lanes/node: l=tid&7, hh2=l&1, slot j=l>>2? no: j=l>>1 (0..3); lane walks stride-4,
// 2-wide unroll; combine via shfl_xor(2)+(4). One 64B line per (edge, group).
__device__ __forceinline__ void agg_rec(const uint4* __restrict__ rp, float ad,
                                        float& z, float* acc) {
    uint4 u0 = rp[0], u1 = rp[1];
    float e = __uint_as_float(u0.x) + ad;
    e = (e > 0.f) ? e : NEG_SLOPE * e;
    float p = __expf(e);
    z += p;
    float2 f0 = __half22float2(*(const __half2*)&u0.y);
    float2 f1 = __half22float2(*(const __half2*)&u0.z);
    float2 f2 = __half22float2(*(const __half2*)&u0.w);
    float2 f3 = __half22float2(*(const __half2*)&u1.x);
    float2 f4 = __half22float2(*(const __half2*)&u1.y);
    float2 f5 = __half22float2(*(const __half2*)&u1.z);
    acc[0] += p * f0.x; acc[1]  += p * f0.y;
    acc[2] += p * f1.x; acc[3]  += p * f1.y;
    acc[4] += p * f2.x; acc[5]  += p * f2.y;
    acc[6] += p * f3.x; acc[7]  += p * f3.y;
    acc[8] += p * f4.x; acc[9]  += p * f4.y;
    acc[10] += p * f5.x; acc[11] += p * f5.y;
}

// mode 0: write fp16 y (layer-0, no relu) -> outYh; mode 1: write fp32 y + relu -> outY
__global__ __launch_bounds__(256) void gat_aggregate_kernel(
    const uint4* __restrict__ Hrec,
    const int* __restrict__ rowptr, const unsigned short* __restrict__ srclist,
    const float* __restrict__ bias,
    _Float16* __restrict__ outYh, float* __restrict__ outY, int mode)
{
    int s    = blockIdx.x & 7;
    int g    = s >> 1;
    int half = s & 1;
    int local = (blockIdx.x >> 3) * AGG_NPB + (threadIdx.x >> 3);
    if (local >= HALFN) return;
    int n   = half * HALFN + local;
    int l   = threadIdx.x & 7;
    int hh2 = l & 1;
    int j   = l >> 1;

    const uint4* gtab = Hrec + (size_t)g * N_NODES * 4;
    float ad = __uint_as_float(gtab[(size_t)n * 4 + hh2 * 2 + 1].w);

    int s0 = rowptr[n], s1 = rowptr[n + 1];
    float z = 0.f;
    float acc[12];
#pragma unroll
    for (int t = 0; t < 12; t++) acc[t] = 0.f;

    int i = s0 + j;
    for (; i + 4 < s1; i += 8) {
        int sa = srclist[i];
        int sb = srclist[i + 4];
        agg_rec(gtab + (size_t)sa * 4 + hh2 * 2, ad, z, acc);
        agg_rec(gtab + (size_t)sb * 4 + hh2 * 2, ad, z, acc);
    }
    if (i < s1) {
        int sa = srclist[i];
        agg_rec(gtab + (size_t)sa * 4 + hh2 * 2, ad, z, acc);
    }

    // combine the 4 slots (bits 1,2 of lane)
#pragma unroll
    for (int m = 2; m <= 4; m <<= 1) {
        z += __shfl_xor(z, m, 64);
#pragma unroll
        for (int t = 0; t < 12; t++) acc[t] += __shfl_xor(acc[t], m, 64);
    }

    if (j == 0) {
        float inv = 1.f / (z + 1e-16f);
        const float* bp = bias + g * 24 + hh2 * 12;
        float o[12];
#pragma unroll
        for (int t = 0; t < 12; t++) o[t] = acc[t] * inv + bp[t];
        if (mode == 0) {
            uint ww[6];
#pragma unroll
            for (int t = 0; t < 6; t++) {
                __half2 hv = __floats2half2_rn(o[2 * t], o[2 * t + 1]);
                ww[t] = *(const uint*)&hv;
            }
            uint2* yp = (uint2*)(outYh + (size_t)n * D_HID + g * 24 + hh2 * 12);
            yp[0] = make_uint2(ww[0], ww[1]);
            yp[1] = make_uint2(ww[2], ww[3]);
            yp[2] = make_uint2(ww[4], ww[5]);
        } else {
#pragma unroll
            for (int t = 0; t < 12; t++) o[t] = fmaxf(o[t], 0.f);
            float4* op = (float4*)(outY + (size_t)n * D_HID + g * 24 + hh2 * 12);
            op[0] = make_float4(o[0], o[1], o[2], o[3]);
            op[1] = make_float4(o[4], o[5], o[6], o[7]);
            op[2] = make_float4(o[8], o[9], o[10], o[11]);
        }
    }
}

// ---------------- final linear (96->40) + bias + log_softmax, thread per node --------
__global__ __launch_bounds__(256) void out_lsm_kernel(
    const float* __restrict__ X, const float* __restrict__ Wout,
    const float* __restrict__ bout, float* __restrict__ out)
{
    __shared__ float Ws[D_HID * N_CLS];
    __shared__ float bs[N_CLS];
    for (int i = threadIdx.x; i < D_HID * N_CLS; i += 256) Ws[i] = Wout[i];
    for (int i = threadIdx.x; i < N_CLS; i += 256) bs[i] = bout[i];
    __syncthreads();

    int n = blockIdx.x * blockDim.x + threadIdx.x;
    if (n >= N_NODES) return;

    float acc[N_CLS];
#pragma unroll
    for (int c = 0; c < N_CLS; c++) acc[c] = bs[c];

    const float4* xp = (const float4*)(X + (size_t)n * D_HID);
    for (int k4 = 0; k4 < D_HID / 4; k4++) {
        float4 xv = xp[k4];
        const float* wrow = &Ws[(k4 * 4) * N_CLS];
#pragma unroll
        for (int c4 = 0; c4 < N_CLS / 4; c4++) {
            float4 wa = *(const float4*)(wrow + c4 * 4);
            float4 wb = *(const float4*)(wrow + N_CLS + c4 * 4);
            float4 wc = *(const float4*)(wrow + 2 * N_CLS + c4 * 4);
            float4 wd = *(const float4*)(wrow + 3 * N_CLS + c4 * 4);
            acc[c4 * 4 + 0] += xv.x * wa.x + xv.y * wb.x + xv.z * wc.x + xv.w * wd.x;
            acc[c4 * 4 + 1] += xv.x * wa.y + xv.y * wb.y + xv.z * wc.y + xv.w * wd.y;
            acc[c4 * 4 + 2] += xv.x * wa.z + xv.y * wb.z + xv.z * wc.z + xv.w * wd.z;
            acc[c4 * 4 + 3] += xv.x * wa.w + xv.y * wb.w + xv.z * wc.w + xv.w * wd.w;
        }
    }

    float m = acc[0];
#pragma unroll
    for (int c = 1; c < N_CLS; c++) m = fmaxf(m, acc[c]);
    float s = 0.f;
#pragma unroll
    for (int c = 0; c < N_CLS; c++) s += __expf(acc[c] - m);
    float lg = __logf(s);

    float4* op = (float4*)(out + (size_t)n * N_CLS);
#pragma unroll
    for (int c4 = 0; c4 < N_CLS / 4; c4++) {
        op[c4] = make_float4(acc[c4 * 4 + 0] - m - lg, acc[c4 * 4 + 1] - m - lg,
                             acc[c4 * 4 + 2] - m - lg, acc[c4 * 4 + 3] - m - lg);
    }
}

extern "C" void kernel_launch(void* const* d_in, const int* in_sizes, int n_in,
                              void* d_out, int out_size, void* d_ws, size_t ws_size,
                              hipStream_t stream)
{
    const float* x    = (const float*)d_in[0];
    const int*   esrc = (const int*)d_in[1];
    const int*   edst = (const int*)d_in[2];
    const float* W0   = (const float*)d_in[3];
    const float* as0  = (const float*)d_in[4];
    const float* ad0  = (const float*)d_in[5];
    const float* b0   = (const float*)d_in[6];
    const float* W1   = (const float*)d_in[7];
    const float* as1  = (const float*)d_in[8];
    const float* ad1  = (const float*)d_in[9];
    const float* b1   = (const float*)d_in[10];
    const float* Wout = (const float*)d_in[11];
    const float* bout = (const float*)d_in[12];
    float* out = (float*)d_out;

    char* p = (char*)d_ws;
    float*    bufY  = (float*)p;    p += (size_t)N_NODES * D_HID * sizeof(float);
    _Float16* bufYh = (_Float16*)p; p += (size_t)N_NODES * D_HID * sizeof(_Float16);
    uint4*    Hrec  = (uint4*)p;    p += (size_t)4 * N_NODES * 64;   // 4 groups x 64B records
    int*   cnt    = (int*)p;   p += ((size_t)N_NODES + 16) * sizeof(int);
    int*   rowptr = (int*)p;   p += ((size_t)N_NODES + 16) * sizeof(int);
    int*   cursor = (int*)p;   p += ((size_t)N_NODES + 16) * sizeof(int);
    unsigned short* srclist = (unsigned short*)p; p += (size_t)N_EDGES * sizeof(unsigned short);
    int*   partials = (int*)p; p += 256;
    _Float16* wt0 = (_Float16*)p; p += (size_t)D_HID * F_IN * sizeof(_Float16);
    _Float16* wt1 = (_Float16*)p; p += (size_t)D_HID * D_HID * sizeof(_Float16);

    int nscan = (N_NODES + 1023) / 1024;   // 49

    // 1. zero cnt + fp16-transpose W0/W1
    pre_kernel<<<133, 256, 0, stream>>>((int4*)cnt, W0, W1, wt0, wt1);
    // 2. hist (XCD-partitioned, int4) + MFMA gemm0 (packed-record epilogue)
    hist_gemm_kernel<<<NHISTB + NGB, 256, 0, stream>>>(
        edst, cnt, x, wt0, as0, ad0, Hrec);
    // 3-4. scan
    scan1_kernel<<<nscan, 256, 0, stream>>>(cnt, cursor, partials, N_NODES);
    scan3_kernel<<<(N_NODES + 255) / 256, 256, 0, stream>>>(cnt, cursor, partials, rowptr,
                                                            N_NODES, nscan);
    // 5. fill CSR (int4)
    fill_part_kernel<<<NHISTB, 256, 0, stream>>>(esrc, edst, cursor, srclist);
    // 6. layer-0 aggregate (XCD-partitioned record gather) -> fp16 y
    gat_aggregate_kernel<<<8 * NAGGB, 256, 0, stream>>>(
        Hrec, rowptr, srclist, b0, bufYh, bufY, 0);
    // 7. layer-1 MFMA gemm (fp16 A, K=96) -> records
    gemm_alpha_kernel<<<NGB, 256, 0, stream>>>(
        bufYh, wt1, as1, ad1, Hrec, N_NODES, D_HID);
    // 8. layer-1 aggregate + relu -> fp32 y
    gat_aggregate_kernel<<<8 * NAGGB, 256, 0, stream>>>(
        Hrec, rowptr, srclist, b1, bufYh, bufY, 1);
    // 9. output linear + log_softmax
    out_lsm_kernel<<<(N_NODES + 255) / 256, 256, 0, stream>>>(bufY, Wout, bout, out);
}

// Round 12
// 161.141 us; speedup vs baseline: 1.6341x; 1.2769x over previous
//
#include <hip/hip_runtime.h>
#include <hip/hip_fp16.h>
#include <math.h>

#define N_NODES 50000
#define N_EDGES 800000
#define F_IN    128
#define D_HID   96
#define NHEAD   8
#define DH      12
#define N_CLS   40
#define NEG_SLOPE 0.2f

#define NPART   (N_NODES / 8)        // 6250 dst nodes per XCD group
#define CKS     64                   // edge chunks
#define CHK     (N_EDGES / CKS)      // 12500 edges per chunk
#define NHB     (8 * CKS)            // 512 hist/fill blocks (group x chunk)

#define GBM 64                       // gemm rows per block
#define NGB ((N_NODES + GBM - 1) / GBM)   // 782
#define WPAD 136                     // LDS W row pad (272B: 16B aligned, 2-way banks = free)

#define HALFN   (N_NODES / 2)        // 25000
#define AGG_NPB 32                   // nodes per aggregate block (256 thr / 8 lanes)
#define NAGGB   ((HALFN + AGG_NPB - 1) / AGG_NPB)   // 782

typedef _Float16 f16x8 __attribute__((ext_vector_type(8)));
typedef float    f32x4 __attribute__((ext_vector_type(4)));

// ---------------- pre: fp16-transpose W0/W1 (no cnt zeroing needed anymore) ----------
__global__ __launch_bounds__(256) void pre_kernel(
    const float* __restrict__ W0, const float* __restrict__ W1,
    _Float16* __restrict__ wt0, _Float16* __restrict__ wt1)
{
    int b = blockIdx.x, t = threadIdx.x;
    if (b < 48) {
        int idx = b * 256 + t;                 // idx = n*128+k (write-coalesced)
        int n = idx >> 7, k = idx & 127;
        wt0[idx] = (_Float16)W0[k * D_HID + n];
    } else {
        int idx = (b - 48) * 256 + t;          // idx = n*96+k
        int n = idx / 96, k = idx - n * 96;
        wt1[idx] = (_Float16)W1[k * D_HID + n];
    }
}

// ---------------- MFMA GEMM core: H = A[M,K] @ W[K,96] (fp16 in, fp32 acc) ------------
// Wave w: rows [bid*64+16w,+16) x 96 cols via 6 x mfma_f32_16x16x32_f16 (layout verified
// r7/m89). Epilogue packs PER-GROUP 64B RECORDS (one cache line per edge-gather):
//   [aS_2q|h0..5][h6..11|aD_2q] [aS_2q+1|h12..17][h18..23|aD_2q+1]
template<bool A16>
__device__ __forceinline__ void gemm_alpha_mfma_body(
    const void* __restrict__ Av, const _Float16* __restrict__ WT,
    const float* __restrict__ asrc, const float* __restrict__ adst,
    uint4* __restrict__ Hrec,
    int M, int K, int bid,
    _Float16 (*Wt)[WPAD], _Float16 (*Hl)[104], float* avl, float* adl)
{
    int tid  = threadIdx.x;
    int lane = tid & 63;
    int w    = tid >> 6;
    int n0   = bid * GBM;

    int cpr = K >> 3;
    int nch = 96 * cpr;
    for (int ch = tid; ch < nch; ch += 256) {
        int row = ch / cpr, off = (ch - row * cpr) << 3;
        *(f16x8*)&Wt[row][off] = *(const f16x8*)&WT[row * K + off];
    }
    if (tid < 96) { avl[tid] = asrc[tid]; adl[tid] = adst[tid]; }
    __syncthreads();

    int c  = lane & 15;
    int kg = lane >> 4;
    int arow = n0 + (w << 4) + c;
    int ar = arow < M ? arow : M - 1;

    f32x4 acc[6];
#pragma unroll
    for (int t = 0; t < 6; t++) acc[t] = (f32x4){0.f, 0.f, 0.f, 0.f};

    for (int k0 = 0; k0 < K; k0 += 32) {
        f16x8 av;
        if constexpr (A16) {
            const _Float16* ap = (const _Float16*)Av + (size_t)ar * K + (kg << 3);
            av = *(const f16x8*)(ap + k0);
        } else {
            const float* ap = (const float*)Av + (size_t)ar * K + (kg << 3);
            float4 a0 = *(const float4*)(ap + k0);
            float4 a1 = *(const float4*)(ap + k0 + 4);
            av[0] = (_Float16)a0.x; av[1] = (_Float16)a0.y;
            av[2] = (_Float16)a0.z; av[3] = (_Float16)a0.w;
            av[4] = (_Float16)a1.x; av[5] = (_Float16)a1.y;
            av[6] = (_Float16)a1.z; av[7] = (_Float16)a1.w;
        }
#pragma unroll
        for (int t = 0; t < 6; t++) {
            f16x8 bv = *(const f16x8*)&Wt[t * 16 + c][k0 + (kg << 3)];
            acc[t] = __builtin_amdgcn_mfma_f32_16x16x32_f16(av, bv, acc[t], 0, 0, 0);
        }
    }

    int rbase = (w << 4) + (kg << 2);
#pragma unroll
    for (int t = 0; t < 6; t++)
#pragma unroll
        for (int r = 0; r < 4; r++)
            Hl[rbase + r][t * 16 + c] = (_Float16)acc[t][r];
    __syncthreads();

    int row = tid >> 2, q = tid & 3;
    int gr = n0 + row;
    if (gr < M) {
        float s0 = 0.f, s1 = 0.f, d0 = 0.f, d1 = 0.f;
#pragma unroll
        for (int j = 0; j < 12; j++) {
            float f = (float)Hl[row][q * 24 + j];
            s0 += f * avl[q * 24 + j];
            d0 += f * adl[q * 24 + j];
        }
#pragma unroll
        for (int j = 12; j < 24; j++) {
            float f = (float)Hl[row][q * 24 + j];
            s1 += f * avl[q * 24 + j];
            d1 += f * adl[q * 24 + j];
        }
        const uint* hp = (const uint*)&Hl[row][q * 24];
        uint4* rec = Hrec + ((size_t)q * N_NODES + gr) * 4;
        rec[0] = make_uint4(__float_as_uint(s0), hp[0], hp[1], hp[2]);
        rec[1] = make_uint4(hp[3], hp[4], hp[5], __float_as_uint(d0));
        rec[2] = make_uint4(__float_as_uint(s1), hp[6], hp[7], hp[8]);
        rec[3] = make_uint4(hp[9], hp[10], hp[11], __float_as_uint(d1));
    }
}

// ------- fused: chunk-hist (blocks [0,NHB), NO global atomics) + gemm0 (rest) --------
// hist block (g=bid&7, c=bid>>3): LDS-histogram chunk c for group g's bin range,
// flush to Hmat[c][bins] as plain uint16 streaming writes.
__global__ __launch_bounds__(256) void hist_gemm_kernel(
    const int* __restrict__ edst, unsigned short* __restrict__ Hmat,
    const float* __restrict__ A, const _Float16* __restrict__ WT,
    const float* __restrict__ asrc, const float* __restrict__ adst,
    uint4* __restrict__ Hrec)
{
    __shared__ __align__(16) char smem[40448];
    if (blockIdx.x < NHB) {
        int* lh = (int*)smem;                      // 25000 B
        int g = blockIdx.x & 7, c = blockIdx.x >> 3;
        int lo = g * NPART;
        for (int i = threadIdx.x; i < NPART; i += 256) lh[i] = 0;
        __syncthreads();
        const int4* d4 = (const int4*)(edst + c * CHK);
        for (int i = threadIdx.x; i < CHK / 4; i += 256) {
            int4 dv = d4[i];
            int a = dv.x - lo, b = dv.y - lo, cc = dv.z - lo, dd = dv.w - lo;
            if ((unsigned)a  < (unsigned)NPART) atomicAdd(&lh[a], 1);
            if ((unsigned)b  < (unsigned)NPART) atomicAdd(&lh[b], 1);
            if ((unsigned)cc < (unsigned)NPART) atomicAdd(&lh[cc], 1);
            if ((unsigned)dd < (unsigned)NPART) atomicAdd(&lh[dd], 1);
        }
        __syncthreads();
        unsigned int* hrow = (unsigned int*)(Hmat + (size_t)c * N_NODES + lo);
        for (int i = threadIdx.x; i < NPART / 2; i += 256)
            hrow[i] = (unsigned)lh[2 * i] | ((unsigned)lh[2 * i + 1] << 16);
    } else {
        _Float16 (*Wt)[WPAD] = (_Float16(*)[WPAD])smem;
        _Float16 (*Hl)[104]  = (_Float16(*)[104])(smem + 26112);
        float* avl = (float*)(smem + 26112 + 13312);
        float* adl = avl + 96;
        gemm_alpha_mfma_body<false>(A, WT, asrc, adst, Hrec, N_NODES, F_IN,
                                    blockIdx.x - NHB, Wt, Hl, avl, adl);
    }
}

// ---------------- standalone gemm (layer 1, fp16 A, K=96) ----------------
__global__ __launch_bounds__(256) void gemm_alpha_kernel(
    const _Float16* __restrict__ A, const _Float16* __restrict__ WT,
    const float* __restrict__ asrc, const float* __restrict__ adst,
    uint4* __restrict__ Hrec, int M, int K)
{
    __shared__ __align__(16) char smem[40448];
    _Float16 (*Wt)[WPAD] = (_Float16(*)[WPAD])smem;
    _Float16 (*Hl)[104]  = (_Float16(*)[104])(smem + 26112);
    float* avl = (float*)(smem + 26112 + 13312);
    float* adl = avl + 96;
    gemm_alpha_mfma_body<true>(A, WT, asrc, adst, Hrec, M, K, blockIdx.x,
                               Wt, Hl, avl, adl);
}

// ---------------- scans (no atomics anywhere) ----------------
// scan1: per bin, sum the 64 chunk counts; block-inclusive scan of sums.
__global__ void scan1_kernel(const unsigned short* __restrict__ Hmat,
                             int* __restrict__ cnt, int* __restrict__ incl,
                             int* __restrict__ partials, int n) {
    __shared__ int sdata[256];
    int t = threadIdx.x;
    int base = blockIdx.x * 1024 + t * 4;
    int v[4] = {0, 0, 0, 0};
    if (base + 4 <= n) {
        for (int c = 0; c < CKS; c++) {
            ushort4 h = *(const ushort4*)&Hmat[(size_t)c * N_NODES + base];
            v[0] += h.x; v[1] += h.y; v[2] += h.z; v[3] += h.w;
        }
    } else if (base < n) {
        for (int c = 0; c < CKS; c++)
#pragma unroll
            for (int j = 0; j < 4; j++)
                if (base + j < n) v[j] += Hmat[(size_t)c * N_NODES + base + j];
    }
#pragma unroll
    for (int j = 0; j < 4; j++) if (base + j < n) cnt[base + j] = v[j];
    v[1] += v[0]; v[2] += v[1]; v[3] += v[2];
    sdata[t] = v[3];
    __syncthreads();
    for (int off = 1; off < 256; off <<= 1) {
        int x = (t >= off) ? sdata[t - off] : 0;
        __syncthreads();
        sdata[t] += x;
        __syncthreads();
    }
    int excl = sdata[t] - v[3];
#pragma unroll
    for (int j = 0; j < 4; j++) { int i = base + j; if (i < n) incl[i] = v[j] + excl; }
    if (t == 255) partials[blockIdx.x] = sdata[255];
}

// scan3: rowptr + per-(chunk,bin) absolute base positions Bmat (streaming, coalesced).
__global__ void scan3_kernel(const int* __restrict__ cnt, const int* __restrict__ incl,
                             const int* __restrict__ partials,
                             const unsigned short* __restrict__ Hmat,
                             int* __restrict__ Bmat, int* __restrict__ rowptr,
                             int n, int nb) {
    int i = blockIdx.x * blockDim.x + threadIdx.x;
    if (i >= n) return;
    int myb = i >> 10;
    int psum = 0;
    for (int b = 0; b < nb; b++) psum += (b < myb) ? partials[b] : 0;
    int v = incl[i] + psum;
    rowptr[i + 1] = v;
    if (i == 0) rowptr[0] = 0;
    int running = v - cnt[i];
    for (int c = 0; c < CKS; c++) {
        Bmat[(size_t)c * N_NODES + i] = running;
        running += Hmat[(size_t)c * N_NODES + i];
    }
}

// fill: LDS cursor from Bmat slice; LDS atomics only; plain scattered srclist stores.
__global__ __launch_bounds__(256) void fill_kernel(
    const int* __restrict__ esrc, const int* __restrict__ edst,
    const int* __restrict__ Bmat, unsigned short* __restrict__ srclist)
{
    __shared__ int cur[NPART];
    int g = blockIdx.x & 7, c = blockIdx.x >> 3;
    int lo = g * NPART;
    const int* brow = Bmat + (size_t)c * N_NODES + lo;
    for (int i = threadIdx.x; i < NPART; i += 256) cur[i] = brow[i];
    __syncthreads();
    int base = c * CHK;
    const int4* d4 = (const int4*)(edst + base);
    const int4* s4 = (const int4*)(esrc + base);
    for (int i = threadIdx.x; i < CHK / 4; i += 256) {
        int4 dv = d4[i], sv = s4[i];
        int a = dv.x - lo, b = dv.y - lo, cc = dv.z - lo, dd = dv.w - lo;
        if ((unsigned)a < (unsigned)NPART) {
            int p = atomicAdd(&cur[a], 1); srclist[p] = (unsigned short)sv.x;
        }
        if ((unsigned)b < (unsigned)NPART) {
            int p = atomicAdd(&cur[b], 1); srclist[p] = (unsigned short)sv.y;
        }
        if ((unsigned)cc < (unsigned)NPART) {
            int p = atomicAdd(&cur[cc], 1); srclist[p] = (unsigned short)sv.z;
        }
        if ((unsigned)dd < (unsigned)NPART) {
            int p = atomicAdd(&cur[dd], 1); srclist[p] = (unsigned short)sv.w;
        }
    }
}

// ---------------- GAT aggregation: packed records, XCD-partitioned (r11-proven) ------
__device__ __forceinline__ void agg_rec(const uint4* __restrict__ rp, float ad,
                                        float& z, float* acc) {
    uint4 u0 = rp[0], u1 = rp[1];
    float e = __uint_as_float(u0.x) + ad;
    e = (e > 0.f) ? e : NEG_SLOPE * e;
    float p = __expf(e);
    z += p;
    float2 f0 = __half22float2(*(const __half2*)&u0.y);
    float2 f1 = __half22float2(*(const __half2*)&u0.z);
    float2 f2 = __half22float2(*(const __half2*)&u0.w);
    float2 f3 = __half22float2(*(const __half2*)&u1.x);
    float2 f4 = __half22float2(*(const __half2*)&u1.y);
    float2 f5 = __half22float2(*(const __half2*)&u1.z);
    acc[0] += p * f0.x; acc[1]  += p * f0.y;
    acc[2] += p * f1.x; acc[3]  += p * f1.y;
    acc[4] += p * f2.x; acc[5]  += p * f2.y;
    acc[6] += p * f3.x; acc[7]  += p * f3.y;
    acc[8] += p * f4.x; acc[9]  += p * f4.y;
    acc[10] += p * f5.x; acc[11] += p * f5.y;
}

__global__ __launch_bounds__(256) void gat_aggregate_kernel(
    const uint4* __restrict__ Hrec,
    const int* __restrict__ rowptr, const unsigned short* __restrict__ srclist,
    const float* __restrict__ bias,
    _Float16* __restrict__ outYh, float* __restrict__ outY, int mode)
{
    int s    = blockIdx.x & 7;
    int g    = s >> 1;
    int half = s & 1;
    int local = (blockIdx.x >> 3) * AGG_NPB + (threadIdx.x >> 3);
    if (local >= HALFN) return;
    int n   = half * HALFN + local;
    int l   = threadIdx.x & 7;
    int hh2 = l & 1;
    int j   = l >> 1;

    const uint4* gtab = Hrec + (size_t)g * N_NODES * 4;
    float ad = __uint_as_float(gtab[(size_t)n * 4 + hh2 * 2 + 1].w);

    int s0 = rowptr[n], s1 = rowptr[n + 1];
    float z = 0.f;
    float acc[12];
#pragma unroll
    for (int t = 0; t < 12; t++) acc[t] = 0.f;

    int i = s0 + j;
    for (; i + 4 < s1; i += 8) {
        int sa = srclist[i];
        int sb = srclist[i + 4];
        agg_rec(gtab + (size_t)sa * 4 + hh2 * 2, ad, z, acc);
        agg_rec(gtab + (size_t)sb * 4 + hh2 * 2, ad, z, acc);
    }
    if (i < s1) {
        int sa = srclist[i];
        agg_rec(gtab + (size_t)sa * 4 + hh2 * 2, ad, z, acc);
    }

#pragma unroll
    for (int m = 2; m <= 4; m <<= 1) {
        z += __shfl_xor(z, m, 64);
#pragma unroll
        for (int t = 0; t < 12; t++) acc[t] += __shfl_xor(acc[t], m, 64);
    }

    if (j == 0) {
        float inv = 1.f / (z + 1e-16f);
        const float* bp = bias + g * 24 + hh2 * 12;
        float o[12];
#pragma unroll
        for (int t = 0; t < 12; t++) o[t] = acc[t] * inv + bp[t];
        if (mode == 0) {
            uint ww[6];
#pragma unroll
            for (int t = 0; t < 6; t++) {
                __half2 hv = __floats2half2_rn(o[2 * t], o[2 * t + 1]);
                ww[t] = *(const uint*)&hv;
            }
            uint2* yp = (uint2*)(outYh + (size_t)n * D_HID + g * 24 + hh2 * 12);
            yp[0] = make_uint2(ww[0], ww[1]);
            yp[1] = make_uint2(ww[2], ww[3]);
            yp[2] = make_uint2(ww[4], ww[5]);
        } else {
#pragma unroll
            for (int t = 0; t < 12; t++) o[t] = fmaxf(o[t], 0.f);
            float4* op = (float4*)(outY + (size_t)n * D_HID + g * 24 + hh2 * 12);
            op[0] = make_float4(o[0], o[1], o[2], o[3]);
            op[1] = make_float4(o[4], o[5], o[6], o[7]);
            op[2] = make_float4(o[8], o[9], o[10], o[11]);
        }
    }
}

// ---------------- final linear (96->40) + bias + log_softmax, thread per node --------
__global__ __launch_bounds__(256) void out_lsm_kernel(
    const float* __restrict__ X, const float* __restrict__ Wout,
    const float* __restrict__ bout, float* __restrict__ out)
{
    __shared__ float Ws[D_HID * N_CLS];
    __shared__ float bs[N_CLS];
    for (int i = threadIdx.x; i < D_HID * N_CLS; i += 256) Ws[i] = Wout[i];
    for (int i = threadIdx.x; i < N_CLS; i += 256) bs[i] = bout[i];
    __syncthreads();

    int n = blockIdx.x * blockDim.x + threadIdx.x;
    if (n >= N_NODES) return;

    float acc[N_CLS];
#pragma unroll
    for (int c = 0; c < N_CLS; c++) acc[c] = bs[c];

    const float4* xp = (const float4*)(X + (size_t)n * D_HID);
    for (int k4 = 0; k4 < D_HID / 4; k4++) {
        float4 xv = xp[k4];
        const float* wrow = &Ws[(k4 * 4) * N_CLS];
#pragma unroll
        for (int c4 = 0; c4 < N_CLS / 4; c4++) {
            float4 wa = *(const float4*)(wrow + c4 * 4);
            float4 wb = *(const float4*)(wrow + N_CLS + c4 * 4);
            float4 wc = *(const float4*)(wrow + 2 * N_CLS + c4 * 4);
            float4 wd = *(const float4*)(wrow + 3 * N_CLS + c4 * 4);
            acc[c4 * 4 + 0] += xv.x * wa.x + xv.y * wb.x + xv.z * wc.x + xv.w * wd.x;
            acc[c4 * 4 + 1] += xv.x * wa.y + xv.y * wb.y + xv.z * wc.y + xv.w * wd.y;
            acc[c4 * 4 + 2] += xv.x * wa.z + xv.y * wb.z + xv.z * wc.z + xv.w * wd.z;
            acc[c4 * 4 + 3] += xv.x * wa.w + xv.y * wb.w + xv.z * wc.w + xv.w * wd.w;
        }
    }

    float m = acc[0];
#pragma unroll
    for (int c = 1; c < N_CLS; c++) m = fmaxf(m, acc[c]);
    float s = 0.f;
#pragma unroll
    for (int c = 0; c < N_CLS; c++) s += __expf(acc[c] - m);
    float lg = __logf(s);

    float4* op = (float4*)(out + (size_t)n * N_CLS);
#pragma unroll
    for (int c4 = 0; c4 < N_CLS / 4; c4++) {
        op[c4] = make_float4(acc[c4 * 4 + 0] - m - lg, acc[c4 * 4 + 1] - m - lg,
                             acc[c4 * 4 + 2] - m - lg, acc[c4 * 4 + 3] - m - lg);
    }
}

extern "C" void kernel_launch(void* const* d_in, const int* in_sizes, int n_in,
                              void* d_out, int out_size, void* d_ws, size_t ws_size,
                              hipStream_t stream)
{
    const float* x    = (const float*)d_in[0];
    const int*   esrc = (const int*)d_in[1];
    const int*   edst = (const int*)d_in[2];
    const float* W0   = (const float*)d_in[3];
    const float* as0  = (const float*)d_in[4];
    const float* ad0  = (const float*)d_in[5];
    const float* b0   = (const float*)d_in[6];
    const float* W1   = (const float*)d_in[7];
    const float* as1  = (const float*)d_in[8];
    const float* ad1  = (const float*)d_in[9];
    const float* b1   = (const float*)d_in[10];
    const float* Wout = (const float*)d_in[11];
    const float* bout = (const float*)d_in[12];
    float* out = (float*)d_out;

    char* p = (char*)d_ws;
    float*    bufY  = (float*)p;    p += (size_t)N_NODES * D_HID * sizeof(float);
    _Float16* bufYh = (_Float16*)p; p += (size_t)N_NODES * D_HID * sizeof(_Float16);
    uint4*    Hrec  = (uint4*)p;    p += (size_t)4 * N_NODES * 64;   // 4 groups x 64B records
    int*   rowptr = (int*)p;   p += ((size_t)N_NODES + 16) * sizeof(int);
    int*   cnt    = (int*)p;   p += ((size_t)N_NODES + 16) * sizeof(int);
    int*   incl   = (int*)p;   p += ((size_t)N_NODES + 16) * sizeof(int);
    unsigned short* srclist = (unsigned short*)p; p += (size_t)N_EDGES * sizeof(unsigned short);
    int*   partials = (int*)p; p += 256;
    _Float16* wt0 = (_Float16*)p; p += (size_t)D_HID * F_IN * sizeof(_Float16);
    _Float16* wt1 = (_Float16*)p; p += (size_t)D_HID * D_HID * sizeof(_Float16);

    // aliases with disjoint lifetimes (CSR build phase vs layer outputs):
    // Hmat [CKS][N_NODES] uint16 (6.4MB) in bufYh (9.6MB): dead before agg0 writes bufYh.
    // Bmat [CKS][N_NODES] int (12.8MB) in bufY (19.2MB): dead before agg1 writes bufY.
    unsigned short* Hmat = (unsigned short*)bufYh;
    int*            Bmat = (int*)bufY;

    int nscan = (N_NODES + 1023) / 1024;   // 49

    // 1. fp16-transpose W0/W1
    pre_kernel<<<84, 256, 0, stream>>>(W0, W1, wt0, wt1);
    // 2. chunk-hist (LDS atomics only) + MFMA gemm0 (packed-record epilogue)
    hist_gemm_kernel<<<NHB + NGB, 256, 0, stream>>>(
        edst, Hmat, x, wt0, as0, ad0, Hrec);
    // 3. per-bin chunk-sum + block scan
    scan1_kernel<<<nscan, 256, 0, stream>>>(Hmat, cnt, incl, partials, N_NODES);
    // 4. rowptr + per-(chunk,bin) base positions
    scan3_kernel<<<(N_NODES + 255) / 256, 256, 0, stream>>>(
        cnt, incl, partials, Hmat, Bmat, rowptr, N_NODES, nscan);
    // 5. fill CSR (LDS cursor, no global atomics)
    fill_kernel<<<NHB, 256, 0, stream>>>(esrc, edst, Bmat, srclist);
    // 6. layer-0 aggregate (XCD-partitioned record gather) -> fp16 y
    gat_aggregate_kernel<<<8 * NAGGB, 256, 0, stream>>>(
        Hrec, rowptr, srclist, b0, bufYh, bufY, 0);
    // 7. layer-1 MFMA gemm (fp16 A, K=96) -> records
    gemm_alpha_kernel<<<NGB, 256, 0, stream>>>(
        bufYh, wt1, as1, ad1, Hrec, N_NODES, D_HID);
    // 8. layer-1 aggregate + relu -> fp32 y
    gat_aggregate_kernel<<<8 * NAGGB, 256, 0, stream>>>(
        Hrec, rowptr, srclist, b1, bufYh, bufY, 1);
    // 9. output linear + log_softmax
    out_lsm_kernel<<<(N_NODES + 255) / 256, 256, 0, stream>>>(bufY, Wout, bout, out);
}